// Round 4
// baseline (1869.973 us; speedup 1.0000x reference)
//
#include <hip/hip_runtime.h>

#define F 128
static const int N0 = 100000, N1 = 25000, N2 = 6250;

typedef unsigned short u16;
typedef unsigned int   u32;

__device__ __forceinline__ float bf2f(u16 u) {
    union { u32 i; float f; } v; v.i = ((u32)u) << 16; return v.f;
}
__device__ __forceinline__ u16 f2bf(float f) {
    u32 u = __float_as_uint(f);
    u += 0x7fff + ((u >> 16) & 1);   // RNE
    return (u16)(u >> 16);
}

// ---- int histogram: cnt[idx[e]]++ ----
__global__ __launch_bounds__(256) void k_counti(const int* __restrict__ idx,
                                                int* __restrict__ cnt, int E) {
    int e = blockIdx.x * 256 + threadIdx.x;
    if (e < E) atomicAdd(&cnt[idx[e]], 1);
}

// ---- single-block exclusive scan: rowptr[0..n] from cnt[0..n); cursor=rowptr copy ----
__global__ __launch_bounds__(1024) void k_scan(const int* __restrict__ cnt,
                                               int* __restrict__ rowptr,
                                               int* __restrict__ cursor, int n) {
    __shared__ int tot[1024];
    int tid = threadIdx.x;
    int per = (n + 1023) >> 10;
    int s = tid * per; if (s > n) s = n;
    int e = s + per;   if (e > n) e = n;
    int sum = 0;
    for (int i = s; i < e; i++) sum += cnt[i];
    tot[tid] = sum;
    __syncthreads();
    for (int d = 1; d < 1024; d <<= 1) {
        int t = (tid >= d) ? tot[tid - d] : 0;
        __syncthreads();
        tot[tid] += t;
        __syncthreads();
    }
    int off = (tid > 0) ? tot[tid - 1] : 0;
    for (int i = s; i < e; i++) { rowptr[i] = off; cursor[i] = off; off += cnt[i]; }
    if (tid == 1023) rowptr[n] = off;
}

// ---- CSR fill: col[pos] = src, pos allocated via cursor[dst] ----
__global__ __launch_bounds__(256) void k_fill(const int* __restrict__ src,
                                              const int* __restrict__ dst,
                                              int* __restrict__ cursor,
                                              int* __restrict__ col, int E) {
    int e = blockIdx.x * 256 + threadIdx.x;
    if (e < E) {
        int pos = atomicAdd(&cursor[dst[e]], 1);
        col[pos] = src[e];
    }
}

// ---- wave-per-row CSR gather over bf16 feature rows ----
// MODE 0: mean  — out = sum(feat[col]) / deg, 0 if deg==0
// MODE 1: gcn   — out = rsqrt0(deg_dst) * sum(feat[col] * rsqrt0(outdeg[col]))
template <int MODE>
__global__ __launch_bounds__(256) void k_gather(const u16* __restrict__ feat,
                                                const int* __restrict__ rowptr,
                                                const int* __restrict__ col,
                                                const int* __restrict__ outdeg,
                                                u16* __restrict__ out, int M) {
    int wv = (blockIdx.x * 256 + threadIdx.x) >> 6;   // one wave per dst row
    if (wv >= M) return;                               // wave-uniform
    int lane = threadIdx.x & 63;
    int beg = rowptr[wv], end = rowptr[wv + 1];
    float a0 = 0.f, a1 = 0.f;
    for (int j = beg; j < end; j++) {
        int c = col[j];                                // uniform addr -> broadcast
        float s = 1.f;
        if (MODE == 1) { int od = outdeg[c]; s = od > 0 ? rsqrtf((float)od) : 0.f; }
        ushort2 u = *(const ushort2*)&feat[(size_t)c * F + (lane << 1)];
        a0 += bf2f(u.x) * s;
        a1 += bf2f(u.y) * s;
    }
    int deg = end - beg;
    float fs = (MODE == 0) ? (deg > 0 ? 1.f / (float)deg : 0.f)
                           : (deg > 0 ? rsqrtf((float)deg) : 0.f);
    ushort2 o; o.x = f2bf(a0 * fs); o.y = f2bf(a1 * fs);
    *(ushort2*)&out[(size_t)wv * F + (lane << 1)] = o;
}

// ---- tiled matmul: out[M,128] = A[M,K] @ W[K,128] + b ----
// AF32: A is fp32 (raw input X), else bf16.
// MASK: zero output rows whose CSR row is empty (encoder isolated-dst mask).
template <int K, bool AF32, bool MASK>
__global__ __launch_bounds__(256) void k_mm(const void* __restrict__ Ap,
                                            const float* __restrict__ W,
                                            const float* __restrict__ bias,
                                            u16* __restrict__ out,
                                            const int* __restrict__ rowptr,
                                            int M) {
    __shared__ u16 Wl[K * F];
    __shared__ u16 Al[64 * K];
    __shared__ float bl[F];
    int tid = threadIdx.x;
    int m0 = blockIdx.x * 64;

    for (int i = tid; i < K * F; i += 256) Wl[i] = f2bf(W[i]);
    if (tid < F) bl[tid] = bias[tid];
    for (int i = tid; i < 64 * K; i += 256) {
        int r = i / K, c = i % K;
        int gr = m0 + r;
        u16 v = 0;
        if (gr < M) {
            if (AF32) v = f2bf(((const float*)Ap)[(size_t)gr * K + c]);
            else      v = ((const u16*)Ap)[(size_t)gr * K + c];
        }
        Al[i] = v;
    }
    __syncthreads();

    int colg = (tid & 31) << 2;   // 4 consecutive output cols
    int rbase = (tid >> 5) << 3;  // 8 consecutive rows
    float acc[8][4];
#pragma unroll
    for (int j = 0; j < 8; j++)
#pragma unroll
        for (int c = 0; c < 4; c++) acc[j][c] = 0.f;

    for (int k0 = 0; k0 < K; k0 += 4) {
        float w[4][4];
#pragma unroll
        for (int kk = 0; kk < 4; kk++) {
            ushort4 wu = *(const ushort4*)&Wl[(k0 + kk) * F + colg];
            w[kk][0] = bf2f(wu.x); w[kk][1] = bf2f(wu.y);
            w[kk][2] = bf2f(wu.z); w[kk][3] = bf2f(wu.w);
        }
#pragma unroll
        for (int j = 0; j < 8; j++) {
            ushort4 au = *(const ushort4*)&Al[(rbase + j) * K + k0];
            float a0 = bf2f(au.x), a1 = bf2f(au.y), a2 = bf2f(au.z), a3 = bf2f(au.w);
#pragma unroll
            for (int c = 0; c < 4; c++)
                acc[j][c] += a0 * w[0][c] + a1 * w[1][c] + a2 * w[2][c] + a3 * w[3][c];
        }
    }

#pragma unroll
    for (int j = 0; j < 8; j++) {
        int gr = m0 + rbase + j;
        if (gr >= M) continue;
        bool zrow = false;
        if (MASK) zrow = (rowptr[gr + 1] == rowptr[gr]);
        ushort4 o;
        o.x = zrow ? (u16)0 : f2bf(acc[j][0] + bl[colg + 0]);
        o.y = zrow ? (u16)0 : f2bf(acc[j][1] + bl[colg + 1]);
        o.z = zrow ? (u16)0 : f2bf(acc[j][2] + bl[colg + 2]);
        o.w = zrow ? (u16)0 : f2bf(acc[j][3] + bl[colg + 3]);
        *(ushort4*)&out[(size_t)gr * F + colg] = o;
    }
}

// ---- head: softmax(concat(g,d) @ Wh + bh) -> FP32 output (reference dtype) ----
__global__ __launch_bounds__(256) void k_head(const u16* __restrict__ g,
                                              const u16* __restrict__ d,
                                              const float* __restrict__ Wh,
                                              const float* __restrict__ bh,
                                              float* __restrict__ out, int M) {
    __shared__ float Wl[256 * 5];
    __shared__ float bl[8];
    int tid = threadIdx.x;
    for (int i = tid; i < 1280; i += 256) Wl[i] = Wh[i];
    if (tid < 5) bl[tid] = bh[tid];
    __syncthreads();

    int lane = tid & 63;
    int wv = tid >> 6;
    int r0 = blockIdx.x * 32 + wv * 8;
    int k0 = lane << 1;
    for (int i = 0; i < 8; i++) {
        int row = r0 + i;
        if (row < M) {
            ushort2 gu = *(const ushort2*)&g[(size_t)row * F + k0];
            ushort2 du = *(const ushort2*)&d[(size_t)row * F + k0];
            float g0v = bf2f(gu.x), g1v = bf2f(gu.y);
            float d0v = bf2f(du.x), d1v = bf2f(du.y);
            float p[5];
#pragma unroll
            for (int o = 0; o < 5; o++) {
                p[o] = g0v * Wl[k0 * 5 + o] + g1v * Wl[(k0 + 1) * 5 + o] +
                       d0v * Wl[(k0 + 128) * 5 + o] + d1v * Wl[(k0 + 129) * 5 + o];
            }
#pragma unroll
            for (int o = 0; o < 5; o++) {
                float v = p[o];
                v += __shfl_xor(v, 32, 64);
                v += __shfl_xor(v, 16, 64);
                v += __shfl_xor(v, 8, 64);
                v += __shfl_xor(v, 4, 64);
                v += __shfl_xor(v, 2, 64);
                v += __shfl_xor(v, 1, 64);
                p[o] = v + bl[o];
            }
            if (lane == 0) {
                float m = p[0];
#pragma unroll
                for (int o = 1; o < 5; o++) m = fmaxf(m, p[o]);
                float e[5], s = 0.f;
#pragma unroll
                for (int o = 0; o < 5; o++) { e[o] = expf(p[o] - m); s += e[o]; }
                float inv = 1.f / s;
#pragma unroll
                for (int o = 0; o < 5; o++) out[(size_t)row * 5 + o] = e[o] * inv;
            }
        }
    }
}

extern "C" void kernel_launch(void* const* d_in, const int* in_sizes, int n_in,
                              void* d_out, int out_size, void* d_ws, size_t ws_size,
                              hipStream_t stream) {
    const float* X = (const float*)d_in[0];
    const int *g0s = (const int*)d_in[1], *g0d = (const int*)d_in[2];
    const int *g1s = (const int*)d_in[3], *g1d = (const int*)d_in[4];
    const int *g2s = (const int*)d_in[5], *g2d = (const int*)d_in[6];
    const int *i0s = (const int*)d_in[7], *i0d = (const int*)d_in[8];
    const int *i1s = (const int*)d_in[9], *i1d = (const int*)d_in[10];
    const int *dc0s = (const int*)d_in[11], *dc0d = (const int*)d_in[12];
    const int *dc1s = (const int*)d_in[13], *dc1d = (const int*)d_in[14];
    const float *Wemb = (const float*)d_in[15], *bemb = (const float*)d_in[16];
    const float *Wg0 = (const float*)d_in[17], *bg0 = (const float*)d_in[18];
    const float *Wg1 = (const float*)d_in[19], *bg1 = (const float*)d_in[20];
    const float *Wg2 = (const float*)d_in[21], *bg2 = (const float*)d_in[22];
    const float *We0 = (const float*)d_in[23], *be0 = (const float*)d_in[24];
    const float *We1 = (const float*)d_in[25], *be1 = (const float*)d_in[26];
    const float *Wd0 = (const float*)d_in[27], *bd0 = (const float*)d_in[28];
    const float *Wd1 = (const float*)d_in[29], *bd1 = (const float*)d_in[30];
    const float *Wh0 = (const float*)d_in[31], *bh0 = (const float*)d_in[32];
    const float *Wh1 = (const float*)d_in[33], *bh1 = (const float*)d_in[34];
    const float *Wh2 = (const float*)d_in[35], *bh2 = (const float*)d_in[36];
    const int Eg0 = in_sizes[1], Eg1 = in_sizes[3], Eg2 = in_sizes[5];
    const int Ei0 = in_sizes[7], Ei1 = in_sizes[9];
    const int Ed0 = in_sizes[11], Ed1 = in_sizes[13];
    (void)n_in; (void)out_size; (void)ws_size;

    char* wsb = (char*)d_ws;
    size_t off = 0;
    auto alloc = [&](size_t bytes) -> char* {
        char* p = wsb + off;
        off = (off + bytes + 255) & ~(size_t)255;
        return p;
    };
    // feature buffers (bf16)                                  // ~113 MB total
    u16* h0  = (u16*)alloc((size_t)N0 * F * 2);
    u16* h1  = (u16*)alloc((size_t)N1 * F * 2);
    u16* h2  = (u16*)alloc((size_t)N2 * F * 2);
    u16* G0  = (u16*)alloc((size_t)N0 * F * 2);
    u16* G1  = (u16*)alloc((size_t)N1 * F * 2);
    u16* G2  = (u16*)alloc((size_t)N2 * F * 2);
    u16* D1  = (u16*)alloc((size_t)N1 * F * 2);
    u16* agg = (u16*)alloc((size_t)N0 * F * 2);  // gather out; becomes D0 at the end
    u16* prj = (u16*)alloc((size_t)N1 * F * 2);  // decoder projections
    u16* D0  = agg;                              // alias: agg dead after g0's mm
    // CSR scratch (int)
    int* cnt    = (int*)alloc((size_t)(N0 + 1) * 4);
    int* rowptr = (int*)alloc((size_t)(N0 + 1) * 4);
    int* cursor = (int*)alloc((size_t)N0 * 4);
    int* od     = (int*)alloc((size_t)N0 * 4);
    int* col    = (int*)alloc((size_t)Eg0 * 4);  // max edge count
    float* out = (float*)d_out;                  // reference output dtype: fp32

    auto csr = [&](const int* s, const int* d, int E, int Ndst) {
        hipMemsetAsync(cnt, 0, (size_t)Ndst * 4, stream);
        k_counti<<<(E + 255) / 256, 256, 0, stream>>>(d, cnt, E);
        k_scan<<<1, 1024, 0, stream>>>(cnt, rowptr, cursor, Ndst);
        k_fill<<<(E + 255) / 256, 256, 0, stream>>>(s, d, cursor, col, E);
    };
    auto srcdeg = [&](const int* s, int E, int Nsrc) {
        hipMemsetAsync(od, 0, (size_t)Nsrc * 4, stream);
        k_counti<<<(E + 255) / 256, 256, 0, stream>>>(s, od, E);
    };

    // 1. h0 = X @ W_emb + b_emb
    k_mm<32, true, false><<<(N0 + 63) / 64, 256, 0, stream>>>(X, Wemb, bemb, h0, nullptr, N0);

    // 2. h1 = mask(mean_agg(h0, inc0) @ W_enc0 + b)   (project-after-aggregate)
    csr(i0s, i0d, Ei0, N1);
    k_gather<0><<<(N1 * 64 + 255) / 256, 256, 0, stream>>>(h0, rowptr, col, nullptr, prj, N1);
    k_mm<128, false, true><<<(N1 + 63) / 64, 256, 0, stream>>>(prj, We0, be0, h1, rowptr, N1);

    // 3. h2 = mask(mean_agg(h1, inc1) @ W_enc1 + b)
    csr(i1s, i1d, Ei1, N2);
    k_gather<0><<<(N2 * 64 + 255) / 256, 256, 0, stream>>>(h1, rowptr, col, nullptr, prj, N2);
    k_mm<128, false, true><<<(N2 + 63) / 64, 256, 0, stream>>>(prj, We1, be1, h2, rowptr, N2);

    // 4. g2 = GraphConv(h2, g2)
    csr(g2s, g2d, Eg2, N2);
    srcdeg(g2s, Eg2, N2);
    k_gather<1><<<(N2 * 64 + 255) / 256, 256, 0, stream>>>(h2, rowptr, col, od, prj, N2);
    k_mm<128, false, false><<<(N2 + 63) / 64, 256, 0, stream>>>(prj, Wg2, bg2, G2, nullptr, N2);

    // 5. d1 = mean_agg(G2 @ W_dec0 + b, dec0)
    k_mm<128, false, false><<<(N2 + 63) / 64, 256, 0, stream>>>(G2, Wd0, bd0, prj, nullptr, N2);
    csr(dc0s, dc0d, Ed0, N1);
    k_gather<0><<<(N1 * 64 + 255) / 256, 256, 0, stream>>>(prj, rowptr, col, nullptr, D1, N1);

    // 6. g1 = GraphConv(h1, g1)
    csr(g1s, g1d, Eg1, N1);
    srcdeg(g1s, Eg1, N1);
    k_gather<1><<<(N1 * 64 + 255) / 256, 256, 0, stream>>>(h1, rowptr, col, od, agg, N1);
    k_mm<128, false, false><<<(N1 + 63) / 64, 256, 0, stream>>>(agg, Wg1, bg1, G1, nullptr, N1);

    // 7. g0 = GraphConv(h0, g0)   (1.6M edges)
    csr(g0s, g0d, Eg0, N0);
    srcdeg(g0s, Eg0, N0);
    k_gather<1><<<((size_t)N0 * 64 + 255) / 256, 256, 0, stream>>>(h0, rowptr, col, od, agg, N0);
    k_mm<128, false, false><<<(N0 + 63) / 64, 256, 0, stream>>>(agg, Wg0, bg0, G0, nullptr, N0);

    // 8. d0 = mean_agg(D1 @ W_dec1 + b, dec1)   (D0 aliases agg — agg consumed above)
    k_mm<128, false, false><<<(N1 + 63) / 64, 256, 0, stream>>>(D1, Wd1, bd1, prj, nullptr, N1);
    csr(dc1s, dc1d, Ed1, N0);
    k_gather<0><<<((size_t)N0 * 64 + 255) / 256, 256, 0, stream>>>(prj, rowptr, col, nullptr, D0, N0);

    // 9. heads (d2 == g2)
    k_head<<<(N0 + 31) / 32, 256, 0, stream>>>(G0, D0, Wh0, bh0, out, N0);
    k_head<<<(N1 + 31) / 32, 256, 0, stream>>>(G1, D1, Wh1, bh1, out + (size_t)N0 * 5, N1);
    k_head<<<(N2 + 31) / 32, 256, 0, stream>>>(G2, G2, Wh2, bh2, out + (size_t)(N0 + N1) * 5, N2);
}

// Round 5
// 1234.406 us; speedup vs baseline: 1.5149x; 1.5149x over previous
//
#include <hip/hip_runtime.h>

#define F 128
static const int N0 = 100000, N1 = 25000, N2 = 6250;

typedef unsigned short u16;
typedef unsigned int   u32;

__device__ __forceinline__ float bf2f(u16 u) {
    union { u32 i; float f; } v; v.i = ((u32)u) << 16; return v.f;
}
__device__ __forceinline__ u16 f2bf(float f) {
    u32 u = __float_as_uint(f);
    u += 0x7fff + ((u >> 16) & 1);   // RNE
    return (u16)(u >> 16);
}

// ---- int histogram: cnt[idx[e]]++ ----
__global__ __launch_bounds__(256) void k_counti(const int* __restrict__ idx,
                                                int* __restrict__ cnt, int E) {
    int e = blockIdx.x * 256 + threadIdx.x;
    if (e < E) atomicAdd(&cnt[idx[e]], 1);
}

// ---- fused src+dst histogram (GCN graphs: dst->cnt segment, src->od segment) ----
__global__ __launch_bounds__(256) void k_count2(const int* __restrict__ src,
                                                const int* __restrict__ dst,
                                                int* __restrict__ od,
                                                int* __restrict__ cnt, int E) {
    int e = blockIdx.x * 256 + threadIdx.x;
    if (e < E) {
        atomicAdd(&od[src[e]], 1);
        atomicAdd(&cnt[dst[e]], 1);
    }
}

// ---- multi-block exclusive scan over concatenated counts (3 phases) ----
#define SCHUNK 4096  // 1024 threads x 4
__global__ __launch_bounds__(1024) void k_scan1(const int* __restrict__ cnt,
                                                int* __restrict__ partial, int n) {
    __shared__ int red[1024];
    int tid = threadIdx.x;
    int base = blockIdx.x * SCHUNK + tid * 4;
    int s = 0;
#pragma unroll
    for (int j = 0; j < 4; j++) { int i = base + j; if (i < n) s += cnt[i]; }
    red[tid] = s;
    __syncthreads();
    for (int d = 512; d > 0; d >>= 1) {
        if (tid < d) red[tid] += red[tid + d];
        __syncthreads();
    }
    if (tid == 0) partial[blockIdx.x] = red[0];
}

__global__ __launch_bounds__(128) void k_scan2(int* __restrict__ partial, int G) {
    __shared__ int sh[128];
    int tid = threadIdx.x;
    sh[tid] = (tid < G) ? partial[tid] : 0;
    __syncthreads();
    for (int d = 1; d < 128; d <<= 1) {
        int t = (tid >= d) ? sh[tid - d] : 0;
        __syncthreads();
        sh[tid] += t;
        __syncthreads();
    }
    if (tid < G) partial[tid] = (tid > 0) ? sh[tid - 1] : 0;  // exclusive
    if (tid == 127) partial[G] = sh[127];                     // grand total
}

__global__ __launch_bounds__(1024) void k_scan3(const int* __restrict__ cnt,
                                                const int* __restrict__ partial,
                                                int* __restrict__ rowptr,
                                                int* __restrict__ cursor,
                                                int n, int G) {
    __shared__ int red[1024];
    int tid = threadIdx.x;
    int base = blockIdx.x * SCHUNK + tid * 4;
    int v0 = 0, v1 = 0, v2 = 0, v3 = 0;
    if (base + 0 < n) v0 = cnt[base + 0];
    if (base + 1 < n) v1 = cnt[base + 1];
    if (base + 2 < n) v2 = cnt[base + 2];
    if (base + 3 < n) v3 = cnt[base + 3];
    red[tid] = v0 + v1 + v2 + v3;
    __syncthreads();
    for (int d = 1; d < 1024; d <<= 1) {
        int t = (tid >= d) ? red[tid - d] : 0;
        __syncthreads();
        red[tid] += t;
        __syncthreads();
    }
    int off = partial[blockIdx.x] + ((tid > 0) ? red[tid - 1] : 0);
    if (base + 0 < n) { rowptr[base + 0] = off; cursor[base + 0] = off; off += v0; }
    if (base + 1 < n) { rowptr[base + 1] = off; cursor[base + 1] = off; off += v1; }
    if (base + 2 < n) { rowptr[base + 2] = off; cursor[base + 2] = off; off += v2; }
    if (base + 3 < n) { rowptr[base + 3] = off; cursor[base + 3] = off; off += v3; }
    if (blockIdx.x == 0 && tid == 0) rowptr[n] = partial[G];
}

// ---- CSR fill: col[pos] = src, pos allocated via cursor[dst] (global positions) ----
__global__ __launch_bounds__(256) void k_fill(const int* __restrict__ src,
                                              const int* __restrict__ dst,
                                              int* __restrict__ cursor,
                                              int* __restrict__ col, int E) {
    int e = blockIdx.x * 256 + threadIdx.x;
    if (e < E) {
        int pos = atomicAdd(&cursor[dst[e]], 1);
        col[pos] = src[e];
    }
}

// ---- wave-per-row CSR gather over bf16 feature rows ----
// MODE 0: mean  — out = sum(feat[col]) / deg, 0 if deg==0
// MODE 1: gcn   — out = rsqrt0(deg_dst) * sum(feat[col] * rsqrt0(outdeg[col]))
template <int MODE>
__global__ __launch_bounds__(256) void k_gather(const u16* __restrict__ feat,
                                                const int* __restrict__ rowptr,
                                                const int* __restrict__ col,
                                                const int* __restrict__ outdeg,
                                                u16* __restrict__ out, int M) {
    int wv = (blockIdx.x * 256 + threadIdx.x) >> 6;   // one wave per dst row
    if (wv >= M) return;                               // wave-uniform
    int lane = threadIdx.x & 63;
    int beg = rowptr[wv], end = rowptr[wv + 1];
    float a0 = 0.f, a1 = 0.f;
    for (int j = beg; j < end; j++) {
        int c = col[j];                                // uniform addr -> broadcast
        float s = 1.f;
        if (MODE == 1) { int od = outdeg[c]; s = od > 0 ? rsqrtf((float)od) : 0.f; }
        ushort2 u = *(const ushort2*)&feat[(size_t)c * F + (lane << 1)];
        a0 += bf2f(u.x) * s;
        a1 += bf2f(u.y) * s;
    }
    int deg = end - beg;
    float fs = (MODE == 0) ? (deg > 0 ? 1.f / (float)deg : 0.f)
                           : (deg > 0 ? rsqrtf((float)deg) : 0.f);
    ushort2 o; o.x = f2bf(a0 * fs); o.y = f2bf(a1 * fs);
    *(ushort2*)&out[(size_t)wv * F + (lane << 1)] = o;
}

// ---- tiled matmul: out[M,128] = A[M,K] @ W[K,128] + b ----
// AF32: A is fp32 (raw input X), else bf16.
// MASK: zero output rows whose CSR row is empty (encoder isolated-dst mask).
template <int K, bool AF32, bool MASK>
__global__ __launch_bounds__(256) void k_mm(const void* __restrict__ Ap,
                                            const float* __restrict__ W,
                                            const float* __restrict__ bias,
                                            u16* __restrict__ out,
                                            const int* __restrict__ rowptr,
                                            int M) {
    __shared__ u16 Wl[K * F];
    __shared__ u16 Al[64 * K];
    __shared__ float bl[F];
    int tid = threadIdx.x;
    int m0 = blockIdx.x * 64;

    for (int i = tid; i < K * F; i += 256) Wl[i] = f2bf(W[i]);
    if (tid < F) bl[tid] = bias[tid];
    for (int i = tid; i < 64 * K; i += 256) {
        int r = i / K, c = i % K;
        int gr = m0 + r;
        u16 v = 0;
        if (gr < M) {
            if (AF32) v = f2bf(((const float*)Ap)[(size_t)gr * K + c]);
            else      v = ((const u16*)Ap)[(size_t)gr * K + c];
        }
        Al[i] = v;
    }
    __syncthreads();

    int colg = (tid & 31) << 2;   // 4 consecutive output cols
    int rbase = (tid >> 5) << 3;  // 8 consecutive rows
    float acc[8][4];
#pragma unroll
    for (int j = 0; j < 8; j++)
#pragma unroll
        for (int c = 0; c < 4; c++) acc[j][c] = 0.f;

    for (int k0 = 0; k0 < K; k0 += 4) {
        float w[4][4];
#pragma unroll
        for (int kk = 0; kk < 4; kk++) {
            ushort4 wu = *(const ushort4*)&Wl[(k0 + kk) * F + colg];
            w[kk][0] = bf2f(wu.x); w[kk][1] = bf2f(wu.y);
            w[kk][2] = bf2f(wu.z); w[kk][3] = bf2f(wu.w);
        }
#pragma unroll
        for (int j = 0; j < 8; j++) {
            ushort4 au = *(const ushort4*)&Al[(rbase + j) * K + k0];
            float a0 = bf2f(au.x), a1 = bf2f(au.y), a2 = bf2f(au.z), a3 = bf2f(au.w);
#pragma unroll
            for (int c = 0; c < 4; c++)
                acc[j][c] += a0 * w[0][c] + a1 * w[1][c] + a2 * w[2][c] + a3 * w[3][c];
        }
    }

#pragma unroll
    for (int j = 0; j < 8; j++) {
        int gr = m0 + rbase + j;
        if (gr >= M) continue;
        bool zrow = false;
        if (MASK) zrow = (rowptr[gr + 1] == rowptr[gr]);
        ushort4 o;
        o.x = zrow ? (u16)0 : f2bf(acc[j][0] + bl[colg + 0]);
        o.y = zrow ? (u16)0 : f2bf(acc[j][1] + bl[colg + 1]);
        o.z = zrow ? (u16)0 : f2bf(acc[j][2] + bl[colg + 2]);
        o.w = zrow ? (u16)0 : f2bf(acc[j][3] + bl[colg + 3]);
        *(ushort4*)&out[(size_t)gr * F + colg] = o;
    }
}

// ---- head: softmax(concat(g,d) @ Wh + bh) -> FP32 output ----
__global__ __launch_bounds__(256) void k_head(const u16* __restrict__ g,
                                              const u16* __restrict__ d,
                                              const float* __restrict__ Wh,
                                              const float* __restrict__ bh,
                                              float* __restrict__ out, int M) {
    __shared__ float Wl[256 * 5];
    __shared__ float bl[8];
    int tid = threadIdx.x;
    for (int i = tid; i < 1280; i += 256) Wl[i] = Wh[i];
    if (tid < 5) bl[tid] = bh[tid];
    __syncthreads();

    int lane = tid & 63;
    int wv = tid >> 6;
    int r0 = blockIdx.x * 32 + wv * 8;
    int k0 = lane << 1;
    for (int i = 0; i < 8; i++) {
        int row = r0 + i;
        if (row < M) {
            ushort2 gu = *(const ushort2*)&g[(size_t)row * F + k0];
            ushort2 du = *(const ushort2*)&d[(size_t)row * F + k0];
            float g0v = bf2f(gu.x), g1v = bf2f(gu.y);
            float d0v = bf2f(du.x), d1v = bf2f(du.y);
            float p[5];
#pragma unroll
            for (int o = 0; o < 5; o++) {
                p[o] = g0v * Wl[k0 * 5 + o] + g1v * Wl[(k0 + 1) * 5 + o] +
                       d0v * Wl[(k0 + 128) * 5 + o] + d1v * Wl[(k0 + 129) * 5 + o];
            }
#pragma unroll
            for (int o = 0; o < 5; o++) {
                float v = p[o];
                v += __shfl_xor(v, 32, 64);
                v += __shfl_xor(v, 16, 64);
                v += __shfl_xor(v, 8, 64);
                v += __shfl_xor(v, 4, 64);
                v += __shfl_xor(v, 2, 64);
                v += __shfl_xor(v, 1, 64);
                p[o] = v + bl[o];
            }
            if (lane == 0) {
                float m = p[0];
#pragma unroll
                for (int o = 1; o < 5; o++) m = fmaxf(m, p[o]);
                float e[5], s = 0.f;
#pragma unroll
                for (int o = 0; o < 5; o++) { e[o] = expf(p[o] - m); s += e[o]; }
                float inv = 1.f / s;
#pragma unroll
                for (int o = 0; o < 5; o++) out[(size_t)row * 5 + o] = e[o] * inv;
            }
        }
    }
}

extern "C" void kernel_launch(void* const* d_in, const int* in_sizes, int n_in,
                              void* d_out, int out_size, void* d_ws, size_t ws_size,
                              hipStream_t stream) {
    const float* X = (const float*)d_in[0];
    const int *g0s = (const int*)d_in[1], *g0d = (const int*)d_in[2];
    const int *g1s = (const int*)d_in[3], *g1d = (const int*)d_in[4];
    const int *g2s = (const int*)d_in[5], *g2d = (const int*)d_in[6];
    const int *i0s = (const int*)d_in[7], *i0d = (const int*)d_in[8];
    const int *i1s = (const int*)d_in[9], *i1d = (const int*)d_in[10];
    const int *dc0s = (const int*)d_in[11], *dc0d = (const int*)d_in[12];
    const int *dc1s = (const int*)d_in[13], *dc1d = (const int*)d_in[14];
    const float *Wemb = (const float*)d_in[15], *bemb = (const float*)d_in[16];
    const float *Wg0 = (const float*)d_in[17], *bg0 = (const float*)d_in[18];
    const float *Wg1 = (const float*)d_in[19], *bg1 = (const float*)d_in[20];
    const float *Wg2 = (const float*)d_in[21], *bg2 = (const float*)d_in[22];
    const float *We0 = (const float*)d_in[23], *be0 = (const float*)d_in[24];
    const float *We1 = (const float*)d_in[25], *be1 = (const float*)d_in[26];
    const float *Wd0 = (const float*)d_in[27], *bd0 = (const float*)d_in[28];
    const float *Wd1 = (const float*)d_in[29], *bd1 = (const float*)d_in[30];
    const float *Wh0 = (const float*)d_in[31], *bh0 = (const float*)d_in[32];
    const float *Wh1 = (const float*)d_in[33], *bh1 = (const float*)d_in[34];
    const float *Wh2 = (const float*)d_in[35], *bh2 = (const float*)d_in[36];
    const int Eg0 = in_sizes[1], Eg1 = in_sizes[3], Eg2 = in_sizes[5];
    const int Ei0 = in_sizes[7], Ei1 = in_sizes[9];
    const int Ed0 = in_sizes[11], Ed1 = in_sizes[13];
    (void)n_in; (void)out_size; (void)ws_size;

    // --- concatenated CSR row segments (7 graphs, dst-row counts) ---
    // order: inc0(N1), inc1(N2), g2(N2), dec0(N1), g1(N1), g0(N0), dec1(N0)
    const int B_I0 = 0;
    const int B_I1 = B_I0 + N1;
    const int B_G2 = B_I1 + N2;
    const int B_D0 = B_G2 + N2;
    const int B_G1 = B_D0 + N1;
    const int B_G0 = B_G1 + N1;
    const int B_D1 = B_G0 + N0;
    const int NROWS = B_D1 + N0;                  // 287500
    const int ETOT  = Eg0 + Eg1 + Eg2 + Ei0 + Ei1 + Ed0 + Ed1;
    // out-degree segments for the 3 GCN graphs
    const int OB_G0 = 0, OB_G1 = N0, OB_G2 = N0 + N1;
    const int NOD = N0 + N1 + N2;                 // 131250
    const int G = (NROWS + SCHUNK - 1) / SCHUNK;  // scan blocks (71)

    char* wsb = (char*)d_ws;
    size_t off = 0;
    auto alloc = [&](size_t bytes) -> char* {
        char* p = wsb + off;
        off = (off + bytes + 255) & ~(size_t)255;
        return p;
    };
    // feature buffers (bf16)
    u16* h0  = (u16*)alloc((size_t)N0 * F * 2);
    u16* h1  = (u16*)alloc((size_t)N1 * F * 2);
    u16* h2  = (u16*)alloc((size_t)N2 * F * 2);
    u16* G0  = (u16*)alloc((size_t)N0 * F * 2);
    u16* G1  = (u16*)alloc((size_t)N1 * F * 2);
    u16* G2  = (u16*)alloc((size_t)N2 * F * 2);
    u16* D1  = (u16*)alloc((size_t)N1 * F * 2);
    u16* agg = (u16*)alloc((size_t)N0 * F * 2);  // gather out; becomes D0 at the end
    u16* prj = (u16*)alloc((size_t)N1 * F * 2);  // decoder projections
    u16* D0  = agg;                              // alias: agg dead after g0's mm
    // concatenated CSR scratch
    int* cnt    = (int*)alloc((size_t)NROWS * 4);
    int* rowptr = (int*)alloc((size_t)(NROWS + 1) * 4);
    int* cursor = (int*)alloc((size_t)NROWS * 4);
    int* od     = (int*)alloc((size_t)NOD * 4);
    int* col    = (int*)alloc((size_t)ETOT * 4);
    int* part   = (int*)alloc((size_t)(G + 1) * 4);
    float* out = (float*)d_out;

    // ---- phase A: build all CSRs up front ----
    hipMemsetAsync(cnt, 0, (size_t)NROWS * 4, stream);
    hipMemsetAsync(od, 0, (size_t)NOD * 4, stream);
    k_count2<<<(Eg0 + 255) / 256, 256, 0, stream>>>(g0s, g0d, od + OB_G0, cnt + B_G0, Eg0);
    k_count2<<<(Eg1 + 255) / 256, 256, 0, stream>>>(g1s, g1d, od + OB_G1, cnt + B_G1, Eg1);
    k_count2<<<(Eg2 + 255) / 256, 256, 0, stream>>>(g2s, g2d, od + OB_G2, cnt + B_G2, Eg2);
    k_counti<<<(Ei0 + 255) / 256, 256, 0, stream>>>(i0d, cnt + B_I0, Ei0);
    k_counti<<<(Ei1 + 255) / 256, 256, 0, stream>>>(i1d, cnt + B_I1, Ei1);
    k_counti<<<(Ed0 + 255) / 256, 256, 0, stream>>>(dc0d, cnt + B_D0, Ed0);
    k_counti<<<(Ed1 + 255) / 256, 256, 0, stream>>>(dc1d, cnt + B_D1, Ed1);
    k_scan1<<<G, 1024, 0, stream>>>(cnt, part, NROWS);
    k_scan2<<<1, 128, 0, stream>>>(part, G);
    k_scan3<<<G, 1024, 0, stream>>>(cnt, part, rowptr, cursor, NROWS, G);
    k_fill<<<(Ei0 + 255) / 256, 256, 0, stream>>>(i0s, i0d, cursor + B_I0, col, Ei0);
    k_fill<<<(Ei1 + 255) / 256, 256, 0, stream>>>(i1s, i1d, cursor + B_I1, col, Ei1);
    k_fill<<<(Eg2 + 255) / 256, 256, 0, stream>>>(g2s, g2d, cursor + B_G2, col, Eg2);
    k_fill<<<(Ed0 + 255) / 256, 256, 0, stream>>>(dc0s, dc0d, cursor + B_D0, col, Ed0);
    k_fill<<<(Eg1 + 255) / 256, 256, 0, stream>>>(g1s, g1d, cursor + B_G1, col, Eg1);
    k_fill<<<(Eg0 + 255) / 256, 256, 0, stream>>>(g0s, g0d, cursor + B_G0, col, Eg0);
    k_fill<<<(Ed1 + 255) / 256, 256, 0, stream>>>(dc1s, dc1d, cursor + B_D1, col, Ed1);

    // ---- phase B: compute ----
    // 1. h0 = X @ W_emb + b_emb
    k_mm<32, true, false><<<(N0 + 63) / 64, 256, 0, stream>>>(X, Wemb, bemb, h0, nullptr, N0);

    // 2. h1 = mask(mean_agg(h0, inc0) @ W_enc0 + b)   (project-after-aggregate)
    k_gather<0><<<(N1 * 64 + 255) / 256, 256, 0, stream>>>(h0, rowptr + B_I0, col, nullptr, prj, N1);
    k_mm<128, false, true><<<(N1 + 63) / 64, 256, 0, stream>>>(prj, We0, be0, h1, rowptr + B_I0, N1);

    // 3. h2 = mask(mean_agg(h1, inc1) @ W_enc1 + b)
    k_gather<0><<<(N2 * 64 + 255) / 256, 256, 0, stream>>>(h1, rowptr + B_I1, col, nullptr, prj, N2);
    k_mm<128, false, true><<<(N2 + 63) / 64, 256, 0, stream>>>(prj, We1, be1, h2, rowptr + B_I1, N2);

    // 4. g2 = GraphConv(h2, g2)
    k_gather<1><<<(N2 * 64 + 255) / 256, 256, 0, stream>>>(h2, rowptr + B_G2, col, od + OB_G2, prj, N2);
    k_mm<128, false, false><<<(N2 + 63) / 64, 256, 0, stream>>>(prj, Wg2, bg2, G2, nullptr, N2);

    // 5. d1 = mean_agg(G2 @ W_dec0 + b, dec0)
    k_mm<128, false, false><<<(N2 + 63) / 64, 256, 0, stream>>>(G2, Wd0, bd0, prj, nullptr, N2);
    k_gather<0><<<(N1 * 64 + 255) / 256, 256, 0, stream>>>(prj, rowptr + B_D0, col, nullptr, D1, N1);

    // 6. g1 = GraphConv(h1, g1)
    k_gather<1><<<(N1 * 64 + 255) / 256, 256, 0, stream>>>(h1, rowptr + B_G1, col, od + OB_G1, agg, N1);
    k_mm<128, false, false><<<(N1 + 63) / 64, 256, 0, stream>>>(agg, Wg1, bg1, G1, nullptr, N1);

    // 7. g0 = GraphConv(h0, g0)   (1.6M edges)
    k_gather<1><<<((size_t)N0 * 64 + 255) / 256, 256, 0, stream>>>(h0, rowptr + B_G0, col, od + OB_G0, agg, N0);
    k_mm<128, false, false><<<(N0 + 63) / 64, 256, 0, stream>>>(agg, Wg0, bg0, G0, nullptr, N0);

    // 8. d0 = mean_agg(D1 @ W_dec1 + b, dec1)   (D0 aliases agg — agg consumed above)
    k_mm<128, false, false><<<(N1 + 63) / 64, 256, 0, stream>>>(D1, Wd1, bd1, prj, nullptr, N1);
    k_gather<0><<<((size_t)N0 * 64 + 255) / 256, 256, 0, stream>>>(prj, rowptr + B_D1, col, nullptr, D0, N0);

    // 9. heads (d2 == g2)
    k_head<<<(N0 + 31) / 32, 256, 0, stream>>>(G0, D0, Wh0, bh0, out, N0);
    k_head<<<(N1 + 31) / 32, 256, 0, stream>>>(G1, D1, Wh1, bh1, out + (size_t)N0 * 5, N1);
    k_head<<<(N2 + 31) / 32, 256, 0, stream>>>(G2, G2, Wh2, bh2, out + (size_t)(N0 + N1) * 5, N2);
}

// Round 6
// 1111.103 us; speedup vs baseline: 1.6830x; 1.1110x over previous
//
#include <hip/hip_runtime.h>

#define F 128
static const int N0 = 100000, N1 = 25000, N2 = 6250;

typedef unsigned short u16;
typedef unsigned int   u32;

__device__ __forceinline__ float bf2f(u16 u) {
    union { u32 i; float f; } v; v.i = ((u32)u) << 16; return v.f;
}
__device__ __forceinline__ u16 f2bf(float f) {
    u32 u = __float_as_uint(f);
    u += 0x7fff + ((u >> 16) & 1);   // RNE
    return (u16)(u >> 16);
}

// ---- int histogram: cnt[idx[e]]++ ----
__global__ __launch_bounds__(256) void k_counti(const int* __restrict__ idx,
                                                int* __restrict__ cnt, int E) {
    int e = blockIdx.x * 256 + threadIdx.x;
    if (e < E) atomicAdd(&cnt[idx[e]], 1);
}

// ---- fused src+dst histogram (GCN graphs: dst->cnt segment, src->od segment) ----
__global__ __launch_bounds__(256) void k_count2(const int* __restrict__ src,
                                                const int* __restrict__ dst,
                                                int* __restrict__ od,
                                                int* __restrict__ cnt, int E) {
    int e = blockIdx.x * 256 + threadIdx.x;
    if (e < E) {
        atomicAdd(&od[src[e]], 1);
        atomicAdd(&cnt[dst[e]], 1);
    }
}

// ---- multi-block exclusive scan over concatenated counts (3 phases) ----
#define SCHUNK 4096  // 1024 threads x 4
__global__ __launch_bounds__(1024) void k_scan1(const int* __restrict__ cnt,
                                                int* __restrict__ partial, int n) {
    __shared__ int red[1024];
    int tid = threadIdx.x;
    int base = blockIdx.x * SCHUNK + tid * 4;
    int s = 0;
#pragma unroll
    for (int j = 0; j < 4; j++) { int i = base + j; if (i < n) s += cnt[i]; }
    red[tid] = s;
    __syncthreads();
    for (int d = 512; d > 0; d >>= 1) {
        if (tid < d) red[tid] += red[tid + d];
        __syncthreads();
    }
    if (tid == 0) partial[blockIdx.x] = red[0];
}

__global__ __launch_bounds__(128) void k_scan2(int* __restrict__ partial, int G) {
    __shared__ int sh[128];
    int tid = threadIdx.x;
    sh[tid] = (tid < G) ? partial[tid] : 0;
    __syncthreads();
    for (int d = 1; d < 128; d <<= 1) {
        int t = (tid >= d) ? sh[tid - d] : 0;
        __syncthreads();
        sh[tid] += t;
        __syncthreads();
    }
    if (tid < G) partial[tid] = (tid > 0) ? sh[tid - 1] : 0;  // exclusive
    if (tid == 127) partial[G] = sh[127];                     // grand total
}

__global__ __launch_bounds__(1024) void k_scan3(const int* __restrict__ cnt,
                                                const int* __restrict__ partial,
                                                int* __restrict__ rowptr,
                                                int* __restrict__ cursor,
                                                int n, int G) {
    __shared__ int red[1024];
    int tid = threadIdx.x;
    int base = blockIdx.x * SCHUNK + tid * 4;
    int v0 = 0, v1 = 0, v2 = 0, v3 = 0;
    if (base + 0 < n) v0 = cnt[base + 0];
    if (base + 1 < n) v1 = cnt[base + 1];
    if (base + 2 < n) v2 = cnt[base + 2];
    if (base + 3 < n) v3 = cnt[base + 3];
    red[tid] = v0 + v1 + v2 + v3;
    __syncthreads();
    for (int d = 1; d < 1024; d <<= 1) {
        int t = (tid >= d) ? red[tid - d] : 0;
        __syncthreads();
        red[tid] += t;
        __syncthreads();
    }
    int off = partial[blockIdx.x] + ((tid > 0) ? red[tid - 1] : 0);
    if (base + 0 < n) { rowptr[base + 0] = off; cursor[base + 0] = off; off += v0; }
    if (base + 1 < n) { rowptr[base + 1] = off; cursor[base + 1] = off; off += v1; }
    if (base + 2 < n) { rowptr[base + 2] = off; cursor[base + 2] = off; off += v2; }
    if (base + 3 < n) { rowptr[base + 3] = off; cursor[base + 3] = off; off += v3; }
    if (blockIdx.x == 0 && tid == 0) rowptr[n] = partial[G];
}

// ---- CSR fill: col[pos] = src, pos allocated via cursor[dst] (global positions) ----
__global__ __launch_bounds__(256) void k_fill(const int* __restrict__ src,
                                              const int* __restrict__ dst,
                                              int* __restrict__ cursor,
                                              int* __restrict__ col, int E) {
    int e = blockIdx.x * 256 + threadIdx.x;
    if (e < E) {
        int pos = atomicAdd(&cursor[dst[e]], 1);
        col[pos] = src[e];
    }
}

// ---- wave-per-row CSR gather, 4-wide unrolled for memory-level parallelism ----
// MODE 0: mean  — out = sum(feat[col]) / deg, 0 if deg==0
// MODE 1: gcn   — out = rsqrt0(deg_dst) * sum(feat[col] * rsqrt0(outdeg[col]))
template <int MODE>
__global__ __launch_bounds__(256) void k_gather(const u16* __restrict__ feat,
                                                const int* __restrict__ rowptr,
                                                const int* __restrict__ col,
                                                const int* __restrict__ outdeg,
                                                u16* __restrict__ out, int M) {
    int wv = (blockIdx.x * 256 + threadIdx.x) >> 6;   // one wave per dst row
    if (wv >= M) return;                               // wave-uniform
    int lane = threadIdx.x & 63;
    int fo = lane << 1;
    int beg = rowptr[wv], end = rowptr[wv + 1];
    float a0 = 0.f, a1 = 0.f;
    int j = beg;
    // 4 independent load chains in flight per wave
    for (; j + 4 <= end; j += 4) {
        int c0 = col[j + 0], c1 = col[j + 1], c2 = col[j + 2], c3 = col[j + 3];
        float s0 = 1.f, s1 = 1.f, s2 = 1.f, s3 = 1.f;
        if (MODE == 1) {
            int o0 = outdeg[c0], o1 = outdeg[c1], o2 = outdeg[c2], o3 = outdeg[c3];
            s0 = o0 > 0 ? rsqrtf((float)o0) : 0.f;
            s1 = o1 > 0 ? rsqrtf((float)o1) : 0.f;
            s2 = o2 > 0 ? rsqrtf((float)o2) : 0.f;
            s3 = o3 > 0 ? rsqrtf((float)o3) : 0.f;
        }
        ushort2 u0 = *(const ushort2*)&feat[(size_t)c0 * F + fo];
        ushort2 u1 = *(const ushort2*)&feat[(size_t)c1 * F + fo];
        ushort2 u2 = *(const ushort2*)&feat[(size_t)c2 * F + fo];
        ushort2 u3 = *(const ushort2*)&feat[(size_t)c3 * F + fo];
        a0 += bf2f(u0.x) * s0; a1 += bf2f(u0.y) * s0;
        a0 += bf2f(u1.x) * s1; a1 += bf2f(u1.y) * s1;
        a0 += bf2f(u2.x) * s2; a1 += bf2f(u2.y) * s2;
        a0 += bf2f(u3.x) * s3; a1 += bf2f(u3.y) * s3;
    }
    for (; j < end; j++) {
        int c = col[j];
        float s = 1.f;
        if (MODE == 1) { int o = outdeg[c]; s = o > 0 ? rsqrtf((float)o) : 0.f; }
        ushort2 u = *(const ushort2*)&feat[(size_t)c * F + fo];
        a0 += bf2f(u.x) * s; a1 += bf2f(u.y) * s;
    }
    int deg = end - beg;
    float fs = (MODE == 0) ? (deg > 0 ? 1.f / (float)deg : 0.f)
                           : (deg > 0 ? rsqrtf((float)deg) : 0.f);
    ushort2 o; o.x = f2bf(a0 * fs); o.y = f2bf(a1 * fs);
    *(ushort2*)&out[(size_t)wv * F + fo] = o;
}

// ---- tiled matmul: out[M,128] = A[M,K] @ W[K,128] + b ----
// AF32: A is fp32 (raw input X), else bf16.
// MASK: zero output rows whose CSR row is empty (encoder isolated-dst mask).
template <int K, bool AF32, bool MASK>
__global__ __launch_bounds__(256) void k_mm(const void* __restrict__ Ap,
                                            const float* __restrict__ W,
                                            const float* __restrict__ bias,
                                            u16* __restrict__ out,
                                            const int* __restrict__ rowptr,
                                            int M) {
    __shared__ u16 Wl[K * F];
    __shared__ u16 Al[64 * K];
    __shared__ float bl[F];
    int tid = threadIdx.x;
    int m0 = blockIdx.x * 64;

    for (int i = tid; i < K * F; i += 256) Wl[i] = f2bf(W[i]);
    if (tid < F) bl[tid] = bias[tid];
    for (int i = tid; i < 64 * K; i += 256) {
        int r = i / K, c = i % K;
        int gr = m0 + r;
        u16 v = 0;
        if (gr < M) {
            if (AF32) v = f2bf(((const float*)Ap)[(size_t)gr * K + c]);
            else      v = ((const u16*)Ap)[(size_t)gr * K + c];
        }
        Al[i] = v;
    }
    __syncthreads();

    int colg = (tid & 31) << 2;   // 4 consecutive output cols
    int rbase = (tid >> 5) << 3;  // 8 consecutive rows
    float acc[8][4];
#pragma unroll
    for (int j = 0; j < 8; j++)
#pragma unroll
        for (int c = 0; c < 4; c++) acc[j][c] = 0.f;

    for (int k0 = 0; k0 < K; k0 += 4) {
        float w[4][4];
#pragma unroll
        for (int kk = 0; kk < 4; kk++) {
            ushort4 wu = *(const ushort4*)&Wl[(k0 + kk) * F + colg];
            w[kk][0] = bf2f(wu.x); w[kk][1] = bf2f(wu.y);
            w[kk][2] = bf2f(wu.z); w[kk][3] = bf2f(wu.w);
        }
#pragma unroll
        for (int j = 0; j < 8; j++) {
            ushort4 au = *(const ushort4*)&Al[(rbase + j) * K + k0];
            float a0 = bf2f(au.x), a1 = bf2f(au.y), a2 = bf2f(au.z), a3 = bf2f(au.w);
#pragma unroll
            for (int c = 0; c < 4; c++)
                acc[j][c] += a0 * w[0][c] + a1 * w[1][c] + a2 * w[2][c] + a3 * w[3][c];
        }
    }

#pragma unroll
    for (int j = 0; j < 8; j++) {
        int gr = m0 + rbase + j;
        if (gr >= M) continue;
        bool zrow = false;
        if (MASK) zrow = (rowptr[gr + 1] == rowptr[gr]);
        ushort4 o;
        o.x = zrow ? (u16)0 : f2bf(acc[j][0] + bl[colg + 0]);
        o.y = zrow ? (u16)0 : f2bf(acc[j][1] + bl[colg + 1]);
        o.z = zrow ? (u16)0 : f2bf(acc[j][2] + bl[colg + 2]);
        o.w = zrow ? (u16)0 : f2bf(acc[j][3] + bl[colg + 3]);
        *(ushort4*)&out[(size_t)gr * F + colg] = o;
    }
}

// ---- head: softmax(concat(g,d) @ Wh + bh) -> FP32 output ----
__global__ __launch_bounds__(256) void k_head(const u16* __restrict__ g,
                                              const u16* __restrict__ d,
                                              const float* __restrict__ Wh,
                                              const float* __restrict__ bh,
                                              float* __restrict__ out, int M) {
    __shared__ float Wl[256 * 5];
    __shared__ float bl[8];
    int tid = threadIdx.x;
    for (int i = tid; i < 1280; i += 256) Wl[i] = Wh[i];
    if (tid < 5) bl[tid] = bh[tid];
    __syncthreads();

    int lane = tid & 63;
    int wv = tid >> 6;
    int r0 = blockIdx.x * 32 + wv * 8;
    int k0 = lane << 1;
    for (int i = 0; i < 8; i++) {
        int row = r0 + i;
        if (row < M) {
            ushort2 gu = *(const ushort2*)&g[(size_t)row * F + k0];
            ushort2 du = *(const ushort2*)&d[(size_t)row * F + k0];
            float g0v = bf2f(gu.x), g1v = bf2f(gu.y);
            float d0v = bf2f(du.x), d1v = bf2f(du.y);
            float p[5];
#pragma unroll
            for (int o = 0; o < 5; o++) {
                p[o] = g0v * Wl[k0 * 5 + o] + g1v * Wl[(k0 + 1) * 5 + o] +
                       d0v * Wl[(k0 + 128) * 5 + o] + d1v * Wl[(k0 + 129) * 5 + o];
            }
#pragma unroll
            for (int o = 0; o < 5; o++) {
                float v = p[o];
                v += __shfl_xor(v, 32, 64);
                v += __shfl_xor(v, 16, 64);
                v += __shfl_xor(v, 8, 64);
                v += __shfl_xor(v, 4, 64);
                v += __shfl_xor(v, 2, 64);
                v += __shfl_xor(v, 1, 64);
                p[o] = v + bl[o];
            }
            if (lane == 0) {
                float m = p[0];
#pragma unroll
                for (int o = 1; o < 5; o++) m = fmaxf(m, p[o]);
                float e[5], s = 0.f;
#pragma unroll
                for (int o = 0; o < 5; o++) { e[o] = expf(p[o] - m); s += e[o]; }
                float inv = 1.f / s;
#pragma unroll
                for (int o = 0; o < 5; o++) out[(size_t)row * 5 + o] = e[o] * inv;
            }
        }
    }
}

extern "C" void kernel_launch(void* const* d_in, const int* in_sizes, int n_in,
                              void* d_out, int out_size, void* d_ws, size_t ws_size,
                              hipStream_t stream) {
    const float* X = (const float*)d_in[0];
    const int *g0s = (const int*)d_in[1], *g0d = (const int*)d_in[2];
    const int *g1s = (const int*)d_in[3], *g1d = (const int*)d_in[4];
    const int *g2s = (const int*)d_in[5], *g2d = (const int*)d_in[6];
    const int *i0s = (const int*)d_in[7], *i0d = (const int*)d_in[8];
    const int *i1s = (const int*)d_in[9], *i1d = (const int*)d_in[10];
    const int *dc0s = (const int*)d_in[11], *dc0d = (const int*)d_in[12];
    const int *dc1s = (const int*)d_in[13], *dc1d = (const int*)d_in[14];
    const float *Wemb = (const float*)d_in[15], *bemb = (const float*)d_in[16];
    const float *Wg0 = (const float*)d_in[17], *bg0 = (const float*)d_in[18];
    const float *Wg1 = (const float*)d_in[19], *bg1 = (const float*)d_in[20];
    const float *Wg2 = (const float*)d_in[21], *bg2 = (const float*)d_in[22];
    const float *We0 = (const float*)d_in[23], *be0 = (const float*)d_in[24];
    const float *We1 = (const float*)d_in[25], *be1 = (const float*)d_in[26];
    const float *Wd0 = (const float*)d_in[27], *bd0 = (const float*)d_in[28];
    const float *Wd1 = (const float*)d_in[29], *bd1 = (const float*)d_in[30];
    const float *Wh0 = (const float*)d_in[31], *bh0 = (const float*)d_in[32];
    const float *Wh1 = (const float*)d_in[33], *bh1 = (const float*)d_in[34];
    const float *Wh2 = (const float*)d_in[35], *bh2 = (const float*)d_in[36];
    const int Eg0 = in_sizes[1], Eg1 = in_sizes[3], Eg2 = in_sizes[5];
    const int Ei0 = in_sizes[7], Ei1 = in_sizes[9];
    const int Ed0 = in_sizes[11], Ed1 = in_sizes[13];
    (void)n_in; (void)out_size; (void)ws_size;

    // --- concatenated CSR row segments (7 graphs, dst-row counts) ---
    const int B_I0 = 0;
    const int B_I1 = B_I0 + N1;
    const int B_G2 = B_I1 + N2;
    const int B_D0 = B_G2 + N2;
    const int B_G1 = B_D0 + N1;
    const int B_G0 = B_G1 + N1;
    const int B_D1 = B_G0 + N0;
    const int NROWS = B_D1 + N0;                  // 287500
    const int ETOT  = Eg0 + Eg1 + Eg2 + Ei0 + Ei1 + Ed0 + Ed1;
    const int OB_G0 = 0, OB_G1 = N0, OB_G2 = N0 + N1;
    const int NOD = N0 + N1 + N2;                 // 131250
    const int G = (NROWS + SCHUNK - 1) / SCHUNK;  // scan blocks (71)

    char* wsb = (char*)d_ws;
    size_t off = 0;
    auto alloc = [&](size_t bytes) -> char* {
        char* p = wsb + off;
        off = (off + bytes + 255) & ~(size_t)255;
        return p;
    };
    u16* h0  = (u16*)alloc((size_t)N0 * F * 2);
    u16* h1  = (u16*)alloc((size_t)N1 * F * 2);
    u16* h2  = (u16*)alloc((size_t)N2 * F * 2);
    u16* G0  = (u16*)alloc((size_t)N0 * F * 2);
    u16* G1  = (u16*)alloc((size_t)N1 * F * 2);
    u16* G2  = (u16*)alloc((size_t)N2 * F * 2);
    u16* D1  = (u16*)alloc((size_t)N1 * F * 2);
    u16* agg = (u16*)alloc((size_t)N0 * F * 2);  // gather out; becomes D0 at the end
    u16* prj = (u16*)alloc((size_t)N1 * F * 2);  // decoder projections
    u16* D0  = agg;                              // alias: agg dead after g0's mm
    int* cnt    = (int*)alloc((size_t)NROWS * 4);
    int* rowptr = (int*)alloc((size_t)(NROWS + 1) * 4);
    int* cursor = (int*)alloc((size_t)NROWS * 4);
    int* od     = (int*)alloc((size_t)NOD * 4);
    int* col    = (int*)alloc((size_t)ETOT * 4);
    int* part   = (int*)alloc((size_t)(G + 1) * 4);
    float* out = (float*)d_out;

    // ---- phase A: build all CSRs up front ----
    hipMemsetAsync(cnt, 0, (size_t)NROWS * 4, stream);
    hipMemsetAsync(od, 0, (size_t)NOD * 4, stream);
    k_count2<<<(Eg0 + 255) / 256, 256, 0, stream>>>(g0s, g0d, od + OB_G0, cnt + B_G0, Eg0);
    k_count2<<<(Eg1 + 255) / 256, 256, 0, stream>>>(g1s, g1d, od + OB_G1, cnt + B_G1, Eg1);
    k_count2<<<(Eg2 + 255) / 256, 256, 0, stream>>>(g2s, g2d, od + OB_G2, cnt + B_G2, Eg2);
    k_counti<<<(Ei0 + 255) / 256, 256, 0, stream>>>(i0d, cnt + B_I0, Ei0);
    k_counti<<<(Ei1 + 255) / 256, 256, 0, stream>>>(i1d, cnt + B_I1, Ei1);
    k_counti<<<(Ed0 + 255) / 256, 256, 0, stream>>>(dc0d, cnt + B_D0, Ed0);
    k_counti<<<(Ed1 + 255) / 256, 256, 0, stream>>>(dc1d, cnt + B_D1, Ed1);
    k_scan1<<<G, 1024, 0, stream>>>(cnt, part, NROWS);
    k_scan2<<<1, 128, 0, stream>>>(part, G);
    k_scan3<<<G, 1024, 0, stream>>>(cnt, part, rowptr, cursor, NROWS, G);
    k_fill<<<(Ei0 + 255) / 256, 256, 0, stream>>>(i0s, i0d, cursor + B_I0, col, Ei0);
    k_fill<<<(Ei1 + 255) / 256, 256, 0, stream>>>(i1s, i1d, cursor + B_I1, col, Ei1);
    k_fill<<<(Eg2 + 255) / 256, 256, 0, stream>>>(g2s, g2d, cursor + B_G2, col, Eg2);
    k_fill<<<(Ed0 + 255) / 256, 256, 0, stream>>>(dc0s, dc0d, cursor + B_D0, col, Ed0);
    k_fill<<<(Eg1 + 255) / 256, 256, 0, stream>>>(g1s, g1d, cursor + B_G1, col, Eg1);
    k_fill<<<(Eg0 + 255) / 256, 256, 0, stream>>>(g0s, g0d, cursor + B_G0, col, Eg0);
    k_fill<<<(Ed1 + 255) / 256, 256, 0, stream>>>(dc1s, dc1d, cursor + B_D1, col, Ed1);

    // ---- phase B: compute ----
    // 1. h0 = X @ W_emb + b_emb
    k_mm<32, true, false><<<(N0 + 63) / 64, 256, 0, stream>>>(X, Wemb, bemb, h0, nullptr, N0);

    // 2. h1 = mask(mean_agg(h0, inc0) @ W_enc0 + b)   (project-after-aggregate)
    k_gather<0><<<(N1 * 64 + 255) / 256, 256, 0, stream>>>(h0, rowptr + B_I0, col, nullptr, prj, N1);
    k_mm<128, false, true><<<(N1 + 63) / 64, 256, 0, stream>>>(prj, We0, be0, h1, rowptr + B_I0, N1);

    // 3. h2 = mask(mean_agg(h1, inc1) @ W_enc1 + b)
    k_gather<0><<<(N2 * 64 + 255) / 256, 256, 0, stream>>>(h1, rowptr + B_I1, col, nullptr, prj, N2);
    k_mm<128, false, true><<<(N2 + 63) / 64, 256, 0, stream>>>(prj, We1, be1, h2, rowptr + B_I1, N2);

    // 4. g2 = GraphConv(h2, g2)
    k_gather<1><<<(N2 * 64 + 255) / 256, 256, 0, stream>>>(h2, rowptr + B_G2, col, od + OB_G2, prj, N2);
    k_mm<128, false, false><<<(N2 + 63) / 64, 256, 0, stream>>>(prj, Wg2, bg2, G2, nullptr, N2);

    // 5. d1 = mean_agg(G2 @ W_dec0 + b, dec0)
    k_mm<128, false, false><<<(N2 + 63) / 64, 256, 0, stream>>>(G2, Wd0, bd0, prj, nullptr, N2);
    k_gather<0><<<(N1 * 64 + 255) / 256, 256, 0, stream>>>(prj, rowptr + B_D0, col, nullptr, D1, N1);

    // 6. g1 = GraphConv(h1, g1)
    k_gather<1><<<(N1 * 64 + 255) / 256, 256, 0, stream>>>(h1, rowptr + B_G1, col, od + OB_G1, agg, N1);
    k_mm<128, false, false><<<(N1 + 63) / 64, 256, 0, stream>>>(agg, Wg1, bg1, G1, nullptr, N1);

    // 7. g0 = GraphConv(h0, g0)   (1.6M edges)
    k_gather<1><<<((size_t)N0 * 64 + 255) / 256, 256, 0, stream>>>(h0, rowptr + B_G0, col, od + OB_G0, agg, N0);
    k_mm<128, false, false><<<(N0 + 63) / 64, 256, 0, stream>>>(agg, Wg0, bg0, G0, nullptr, N0);

    // 8. d0 = mean_agg(D1 @ W_dec1 + b, dec1)   (D0 aliases agg — agg consumed above)
    k_mm<128, false, false><<<(N1 + 63) / 64, 256, 0, stream>>>(D1, Wd1, bd1, prj, nullptr, N1);
    k_gather<0><<<((size_t)N0 * 64 + 255) / 256, 256, 0, stream>>>(prj, rowptr + B_D1, col, nullptr, D0, N0);

    // 9. heads (d2 == g2)
    k_head<<<(N0 + 31) / 32, 256, 0, stream>>>(G0, D0, Wh0, bh0, out, N0);
    k_head<<<(N1 + 31) / 32, 256, 0, stream>>>(G1, D1, Wh1, bh1, out + (size_t)N0 * 5, N1);
    k_head<<<(N2 + 31) / 32, 256, 0, stream>>>(G2, G2, Wh2, bh2, out + (size_t)(N0 + N1) * 5, N2);
}

// Round 7
// 977.028 us; speedup vs baseline: 1.9139x; 1.1372x over previous
//
#include <hip/hip_runtime.h>

#define F 128
static const int N0 = 100000, N1 = 25000, N2 = 6250;

typedef unsigned short u16;
typedef unsigned int   u32;
typedef __attribute__((ext_vector_type(8))) short bf16x8;
typedef __attribute__((ext_vector_type(4))) float f32x4;

__device__ __forceinline__ float bf2f(u16 u) {
    union { u32 i; float f; } v; v.i = ((u32)u) << 16; return v.f;
}
__device__ __forceinline__ u16 f2bf(float f) {
    u32 u = __float_as_uint(f);
    u += 0x7fff + ((u >> 16) & 1);   // RNE
    return (u16)(u >> 16);
}

// ---- segment table for fused edge-parallel kernels (7 graphs) ----
struct Seg7 {
    const int* src[7];
    const int* dst[7];
    int end[7];      // cumulative edge-count boundaries
    int cbase[7];    // row-segment base in concatenated cnt/rowptr/cursor
    int obase[7];    // out-degree segment base, -1 if not a GCN graph
};

// ---- fused histogram over all graphs: cnt[dst]++ (+ od[src]++ for GCN) ----
__global__ __launch_bounds__(256) void k_count_all(Seg7 S, int* __restrict__ cnt,
                                                   int* __restrict__ od, int ETOT) {
    int e = blockIdx.x * 256 + threadIdx.x;
    if (e >= ETOT) return;
    int s = 0;
    while (e >= S.end[s]) s++;
    int base = (s == 0) ? 0 : S.end[s - 1];
    int le = e - base;
    int d = S.dst[s][le];
    atomicAdd(&cnt[S.cbase[s] + d], 1);
    int ob = S.obase[s];
    if (ob >= 0) atomicAdd(&od[ob + S.src[s][le]], 1);
}

// ---- fused CSR fill over all graphs ----
__global__ __launch_bounds__(256) void k_fill_all(Seg7 S, int* __restrict__ cursor,
                                                  int* __restrict__ col, int ETOT) {
    int e = blockIdx.x * 256 + threadIdx.x;
    if (e >= ETOT) return;
    int s = 0;
    while (e >= S.end[s]) s++;
    int base = (s == 0) ? 0 : S.end[s - 1];
    int le = e - base;
    int d = S.dst[s][le];
    int pos = atomicAdd(&cursor[S.cbase[s] + d], 1);
    col[pos] = S.src[s][le];
}

// ---- multi-block exclusive scan over concatenated counts (3 phases) ----
#define SCHUNK 4096  // 1024 threads x 4
__global__ __launch_bounds__(1024) void k_scan1(const int* __restrict__ cnt,
                                                int* __restrict__ partial, int n) {
    __shared__ int red[1024];
    int tid = threadIdx.x;
    int base = blockIdx.x * SCHUNK + tid * 4;
    int s = 0;
#pragma unroll
    for (int j = 0; j < 4; j++) { int i = base + j; if (i < n) s += cnt[i]; }
    red[tid] = s;
    __syncthreads();
    for (int d = 512; d > 0; d >>= 1) {
        if (tid < d) red[tid] += red[tid + d];
        __syncthreads();
    }
    if (tid == 0) partial[blockIdx.x] = red[0];
}

__global__ __launch_bounds__(128) void k_scan2(int* __restrict__ partial, int G) {
    __shared__ int sh[128];
    int tid = threadIdx.x;
    sh[tid] = (tid < G) ? partial[tid] : 0;
    __syncthreads();
    for (int d = 1; d < 128; d <<= 1) {
        int t = (tid >= d) ? sh[tid - d] : 0;
        __syncthreads();
        sh[tid] += t;
        __syncthreads();
    }
    if (tid < G) partial[tid] = (tid > 0) ? sh[tid - 1] : 0;  // exclusive
    if (tid == 127) partial[G] = sh[127];                     // grand total
}

__global__ __launch_bounds__(1024) void k_scan3(const int* __restrict__ cnt,
                                                const int* __restrict__ partial,
                                                int* __restrict__ rowptr,
                                                int* __restrict__ cursor,
                                                int n, int G) {
    __shared__ int red[1024];
    int tid = threadIdx.x;
    int base = blockIdx.x * SCHUNK + tid * 4;
    int v0 = 0, v1 = 0, v2 = 0, v3 = 0;
    if (base + 0 < n) v0 = cnt[base + 0];
    if (base + 1 < n) v1 = cnt[base + 1];
    if (base + 2 < n) v2 = cnt[base + 2];
    if (base + 3 < n) v3 = cnt[base + 3];
    red[tid] = v0 + v1 + v2 + v3;
    __syncthreads();
    for (int d = 1; d < 1024; d <<= 1) {
        int t = (tid >= d) ? red[tid - d] : 0;
        __syncthreads();
        red[tid] += t;
        __syncthreads();
    }
    int off = partial[blockIdx.x] + ((tid > 0) ? red[tid - 1] : 0);
    if (base + 0 < n) { rowptr[base + 0] = off; cursor[base + 0] = off; off += v0; }
    if (base + 1 < n) { rowptr[base + 1] = off; cursor[base + 1] = off; off += v1; }
    if (base + 2 < n) { rowptr[base + 2] = off; cursor[base + 2] = off; off += v2; }
    if (base + 3 < n) { rowptr[base + 3] = off; cursor[base + 3] = off; off += v3; }
    if (blockIdx.x == 0 && tid == 0) rowptr[n] = partial[G];
}

// ---- wave-per-row CSR gather, 8-wide unrolled for memory-level parallelism ----
// MODE 0: mean  — out = sum(feat[col]) / deg, 0 if deg==0
// MODE 1: gcn   — out = rsqrt0(deg_dst) * sum(feat[col] * rsqrt0(outdeg[col]))
template <int MODE>
__global__ __launch_bounds__(256) void k_gather(const u16* __restrict__ feat,
                                                const int* __restrict__ rowptr,
                                                const int* __restrict__ col,
                                                const int* __restrict__ outdeg,
                                                u16* __restrict__ out, int M) {
    int wv = (blockIdx.x * 256 + threadIdx.x) >> 6;   // one wave per dst row
    if (wv >= M) return;                               // wave-uniform
    int lane = threadIdx.x & 63;
    int fo = lane << 1;
    int beg = rowptr[wv], end = rowptr[wv + 1];
    float a0 = 0.f, a1 = 0.f;
    int j = beg;
    for (; j + 8 <= end; j += 8) {         // 8 independent load chains
        int cc[8];
#pragma unroll
        for (int t = 0; t < 8; t++) cc[t] = col[j + t];
        float ss[8];
#pragma unroll
        for (int t = 0; t < 8; t++) {
            if (MODE == 1) { int o = outdeg[cc[t]]; ss[t] = o > 0 ? rsqrtf((float)o) : 0.f; }
            else ss[t] = 1.f;
        }
        ushort2 uu[8];
#pragma unroll
        for (int t = 0; t < 8; t++) uu[t] = *(const ushort2*)&feat[(size_t)cc[t] * F + fo];
#pragma unroll
        for (int t = 0; t < 8; t++) { a0 += bf2f(uu[t].x) * ss[t]; a1 += bf2f(uu[t].y) * ss[t]; }
    }
    for (; j < end; j++) {
        int c = col[j];
        float s = 1.f;
        if (MODE == 1) { int o = outdeg[c]; s = o > 0 ? rsqrtf((float)o) : 0.f; }
        ushort2 u = *(const ushort2*)&feat[(size_t)c * F + fo];
        a0 += bf2f(u.x) * s; a1 += bf2f(u.y) * s;
    }
    int deg = end - beg;
    float fs = (MODE == 0) ? (deg > 0 ? 1.f / (float)deg : 0.f)
                           : (deg > 0 ? rsqrtf((float)deg) : 0.f);
    ushort2 o; o.x = f2bf(a0 * fs); o.y = f2bf(a1 * fs);
    *(ushort2*)&out[(size_t)wv * F + fo] = o;
}

// ---- MFMA tiled matmul: out[M,128] = A[M,K] @ W[K,128] + b ----
// 256 threads = 4 waves; tile M=64 (16 rows/wave), N=128 (8 mfma tiles), bf16 MFMA.
// A-frag: A[m=lane&15][k=quad*8+j]; B-frag: B[k=quad*8+j][n=lane&15];
// C/D: col=lane&15, row=quad*4+reg (HW-verified layouts, m89/m120).
template <int K, bool AF32, bool MASK>
__global__ __launch_bounds__(256) void k_mm(const void* __restrict__ Ap,
                                            const float* __restrict__ W,
                                            const float* __restrict__ bias,
                                            u16* __restrict__ out,
                                            const int* __restrict__ rowptr,
                                            int M) {
    const int AST = K + 8;   // pad to spread LDS banks, keep 16B alignment
    const int WST = K + 8;
    __shared__ u16 Al[64 * (K + 8)];
    __shared__ u16 Wt[128 * (K + 8)];   // W transposed: Wt[n][k]
    __shared__ float bl[128];
    int tid = threadIdx.x;
    int m0 = blockIdx.x * 64;

    for (int i = tid; i < K * 128; i += 256) {
        int k = i >> 7, n = i & 127;
        Wt[n * WST + k] = f2bf(W[i]);
    }
    for (int i = tid; i < 64 * K; i += 256) {
        int r = i / K, c = i % K;
        int gr = m0 + r;
        u16 v = 0;
        if (gr < M) {
            if (AF32) v = f2bf(((const float*)Ap)[(size_t)gr * K + c]);
            else      v = ((const u16*)Ap)[(size_t)gr * K + c];
        }
        Al[r * AST + c] = v;
    }
    if (tid < 128) bl[tid] = bias[tid];
    __syncthreads();

    int w = tid >> 6;          // wave id: rows m0 + w*16 .. +15
    int lane = tid & 63;
    int m16 = lane & 15;
    int quad = lane >> 4;

    f32x4 acc[8];
#pragma unroll
    for (int t = 0; t < 8; t++)
#pragma unroll
        for (int r = 0; r < 4; r++) acc[t][r] = 0.f;

    for (int k0 = 0; k0 < K; k0 += 32) {
        bf16x8 af = *(const bf16x8*)&Al[(w * 16 + m16) * AST + k0 + quad * 8];
#pragma unroll
        for (int t = 0; t < 8; t++) {
            bf16x8 bf = *(const bf16x8*)&Wt[(t * 16 + m16) * WST + k0 + quad * 8];
            acc[t] = __builtin_amdgcn_mfma_f32_16x16x32_bf16(af, bf, acc[t], 0, 0, 0);
        }
    }

#pragma unroll
    for (int t = 0; t < 8; t++) {
#pragma unroll
        for (int r = 0; r < 4; r++) {
            int gr = m0 + w * 16 + quad * 4 + r;
            if (gr >= M) continue;
            int gc = t * 16 + m16;
            bool zrow = false;
            if (MASK) zrow = (rowptr[gr + 1] == rowptr[gr]);
            float v = acc[t][r] + bl[gc];
            out[(size_t)gr * F + gc] = zrow ? (u16)0 : f2bf(v);
        }
    }
}

// ---- head: softmax(concat(g,d) @ Wh + bh) -> FP32 output ----
__global__ __launch_bounds__(256) void k_head(const u16* __restrict__ g,
                                              const u16* __restrict__ d,
                                              const float* __restrict__ Wh,
                                              const float* __restrict__ bh,
                                              float* __restrict__ out, int M) {
    __shared__ float Wl[256 * 5];
    __shared__ float bl[8];
    int tid = threadIdx.x;
    for (int i = tid; i < 1280; i += 256) Wl[i] = Wh[i];
    if (tid < 5) bl[tid] = bh[tid];
    __syncthreads();

    int lane = tid & 63;
    int wv = tid >> 6;
    int r0 = blockIdx.x * 32 + wv * 8;
    int k0 = lane << 1;
    for (int i = 0; i < 8; i++) {
        int row = r0 + i;
        if (row < M) {
            ushort2 gu = *(const ushort2*)&g[(size_t)row * F + k0];
            ushort2 du = *(const ushort2*)&d[(size_t)row * F + k0];
            float g0v = bf2f(gu.x), g1v = bf2f(gu.y);
            float d0v = bf2f(du.x), d1v = bf2f(du.y);
            float p[5];
#pragma unroll
            for (int o = 0; o < 5; o++) {
                p[o] = g0v * Wl[k0 * 5 + o] + g1v * Wl[(k0 + 1) * 5 + o] +
                       d0v * Wl[(k0 + 128) * 5 + o] + d1v * Wl[(k0 + 129) * 5 + o];
            }
#pragma unroll
            for (int o = 0; o < 5; o++) {
                float v = p[o];
                v += __shfl_xor(v, 32, 64);
                v += __shfl_xor(v, 16, 64);
                v += __shfl_xor(v, 8, 64);
                v += __shfl_xor(v, 4, 64);
                v += __shfl_xor(v, 2, 64);
                v += __shfl_xor(v, 1, 64);
                p[o] = v + bl[o];
            }
            if (lane == 0) {
                float m = p[0];
#pragma unroll
                for (int o = 1; o < 5; o++) m = fmaxf(m, p[o]);
                float e[5], s = 0.f;
#pragma unroll
                for (int o = 0; o < 5; o++) { e[o] = expf(p[o] - m); s += e[o]; }
                float inv = 1.f / s;
#pragma unroll
                for (int o = 0; o < 5; o++) out[(size_t)row * 5 + o] = e[o] * inv;
            }
        }
    }
}

extern "C" void kernel_launch(void* const* d_in, const int* in_sizes, int n_in,
                              void* d_out, int out_size, void* d_ws, size_t ws_size,
                              hipStream_t stream) {
    const float* X = (const float*)d_in[0];
    const int *g0s = (const int*)d_in[1], *g0d = (const int*)d_in[2];
    const int *g1s = (const int*)d_in[3], *g1d = (const int*)d_in[4];
    const int *g2s = (const int*)d_in[5], *g2d = (const int*)d_in[6];
    const int *i0s = (const int*)d_in[7], *i0d = (const int*)d_in[8];
    const int *i1s = (const int*)d_in[9], *i1d = (const int*)d_in[10];
    const int *dc0s = (const int*)d_in[11], *dc0d = (const int*)d_in[12];
    const int *dc1s = (const int*)d_in[13], *dc1d = (const int*)d_in[14];
    const float *Wemb = (const float*)d_in[15], *bemb = (const float*)d_in[16];
    const float *Wg0 = (const float*)d_in[17], *bg0 = (const float*)d_in[18];
    const float *Wg1 = (const float*)d_in[19], *bg1 = (const float*)d_in[20];
    const float *Wg2 = (const float*)d_in[21], *bg2 = (const float*)d_in[22];
    const float *We0 = (const float*)d_in[23], *be0 = (const float*)d_in[24];
    const float *We1 = (const float*)d_in[25], *be1 = (const float*)d_in[26];
    const float *Wd0 = (const float*)d_in[27], *bd0 = (const float*)d_in[28];
    const float *Wd1 = (const float*)d_in[29], *bd1 = (const float*)d_in[30];
    const float *Wh0 = (const float*)d_in[31], *bh0 = (const float*)d_in[32];
    const float *Wh1 = (const float*)d_in[33], *bh1 = (const float*)d_in[34];
    const float *Wh2 = (const float*)d_in[35], *bh2 = (const float*)d_in[36];
    const int Eg0 = in_sizes[1], Eg1 = in_sizes[3], Eg2 = in_sizes[5];
    const int Ei0 = in_sizes[7], Ei1 = in_sizes[9];
    const int Ed0 = in_sizes[11], Ed1 = in_sizes[13];
    (void)n_in; (void)out_size; (void)ws_size;

    // --- concatenated CSR row segments (7 graphs, dst-row counts) ---
    const int B_I0 = 0;
    const int B_I1 = B_I0 + N1;
    const int B_G2 = B_I1 + N2;
    const int B_D0 = B_G2 + N2;
    const int B_G1 = B_D0 + N1;
    const int B_G0 = B_G1 + N1;
    const int B_D1 = B_G0 + N0;
    const int NROWS = B_D1 + N0;                  // 287500
    const int ETOT  = Eg0 + Eg1 + Eg2 + Ei0 + Ei1 + Ed0 + Ed1;
    const int OB_G0 = 0, OB_G1 = N0, OB_G2 = N0 + N1;
    const int NOD = N0 + N1 + N2;                 // 131250
    const int G = (NROWS + SCHUNK - 1) / SCHUNK;  // scan blocks (71)

    char* wsb = (char*)d_ws;
    size_t off = 0;
    auto alloc = [&](size_t bytes) -> char* {
        char* p = wsb + off;
        off = (off + bytes + 255) & ~(size_t)255;
        return p;
    };
    u16* h0  = (u16*)alloc((size_t)N0 * F * 2);
    u16* h1  = (u16*)alloc((size_t)N1 * F * 2);
    u16* h2  = (u16*)alloc((size_t)N2 * F * 2);
    u16* G0  = (u16*)alloc((size_t)N0 * F * 2);
    u16* G1  = (u16*)alloc((size_t)N1 * F * 2);
    u16* G2  = (u16*)alloc((size_t)N2 * F * 2);
    u16* D1  = (u16*)alloc((size_t)N1 * F * 2);
    u16* agg = (u16*)alloc((size_t)N0 * F * 2);  // gather out; becomes D0 at the end
    u16* prj = (u16*)alloc((size_t)N1 * F * 2);  // decoder projections
    u16* D0  = agg;                              // alias: agg dead after g0's mm
    int* cnt    = (int*)alloc((size_t)NROWS * 4);
    int* rowptr = (int*)alloc((size_t)(NROWS + 1) * 4);
    int* cursor = (int*)alloc((size_t)NROWS * 4);
    int* od     = (int*)alloc((size_t)NOD * 4);
    int* col    = (int*)alloc((size_t)ETOT * 4);
    int* part   = (int*)alloc((size_t)(G + 1) * 4);
    float* out = (float*)d_out;

    // segment table: inc0, inc1, g2, dec0, g1, g0, dec1
    Seg7 S;
    S.src[0] = i0s;  S.dst[0] = i0d;  S.cbase[0] = B_I0; S.obase[0] = -1;
    S.src[1] = i1s;  S.dst[1] = i1d;  S.cbase[1] = B_I1; S.obase[1] = -1;
    S.src[2] = g2s;  S.dst[2] = g2d;  S.cbase[2] = B_G2; S.obase[2] = OB_G2;
    S.src[3] = dc0s; S.dst[3] = dc0d; S.cbase[3] = B_D0; S.obase[3] = -1;
    S.src[4] = g1s;  S.dst[4] = g1d;  S.cbase[4] = B_G1; S.obase[4] = OB_G1;
    S.src[5] = g0s;  S.dst[5] = g0d;  S.cbase[5] = B_G0; S.obase[5] = OB_G0;
    S.src[6] = dc1s; S.dst[6] = dc1d; S.cbase[6] = B_D1; S.obase[6] = -1;
    {
        int Es[7] = {Ei0, Ei1, Eg2, Ed0, Eg1, Eg0, Ed1};
        int acc = 0;
        for (int i = 0; i < 7; i++) { acc += Es[i]; S.end[i] = acc; }
    }

    // ---- phase A: build all CSRs up front ----
    hipMemsetAsync(cnt, 0, (size_t)NROWS * 4, stream);
    hipMemsetAsync(od, 0, (size_t)NOD * 4, stream);
    k_count_all<<<(ETOT + 255) / 256, 256, 0, stream>>>(S, cnt, od, ETOT);
    k_scan1<<<G, 1024, 0, stream>>>(cnt, part, NROWS);
    k_scan2<<<1, 128, 0, stream>>>(part, G);
    k_scan3<<<G, 1024, 0, stream>>>(cnt, part, rowptr, cursor, NROWS, G);
    k_fill_all<<<(ETOT + 255) / 256, 256, 0, stream>>>(S, cursor, col, ETOT);

    // ---- phase B: compute ----
    // 1. h0 = X @ W_emb + b_emb
    k_mm<32, true, false><<<(N0 + 63) / 64, 256, 0, stream>>>(X, Wemb, bemb, h0, nullptr, N0);

    // 2. h1 = mask(mean_agg(h0, inc0) @ W_enc0 + b)   (project-after-aggregate)
    k_gather<0><<<(N1 * 64 + 255) / 256, 256, 0, stream>>>(h0, rowptr + B_I0, col, nullptr, prj, N1);
    k_mm<128, false, true><<<(N1 + 63) / 64, 256, 0, stream>>>(prj, We0, be0, h1, rowptr + B_I0, N1);

    // 3. h2 = mask(mean_agg(h1, inc1) @ W_enc1 + b)
    k_gather<0><<<(N2 * 64 + 255) / 256, 256, 0, stream>>>(h1, rowptr + B_I1, col, nullptr, prj, N2);
    k_mm<128, false, true><<<(N2 + 63) / 64, 256, 0, stream>>>(prj, We1, be1, h2, rowptr + B_I1, N2);

    // 4. g2 = GraphConv(h2, g2)
    k_gather<1><<<(N2 * 64 + 255) / 256, 256, 0, stream>>>(h2, rowptr + B_G2, col, od + OB_G2, prj, N2);
    k_mm<128, false, false><<<(N2 + 63) / 64, 256, 0, stream>>>(prj, Wg2, bg2, G2, nullptr, N2);

    // 5. d1 = mean_agg(G2 @ W_dec0 + b, dec0)
    k_mm<128, false, false><<<(N2 + 63) / 64, 256, 0, stream>>>(G2, Wd0, bd0, prj, nullptr, N2);
    k_gather<0><<<(N1 * 64 + 255) / 256, 256, 0, stream>>>(prj, rowptr + B_D0, col, nullptr, D1, N1);

    // 6. g1 = GraphConv(h1, g1)
    k_gather<1><<<(N1 * 64 + 255) / 256, 256, 0, stream>>>(h1, rowptr + B_G1, col, od + OB_G1, agg, N1);
    k_mm<128, false, false><<<(N1 + 63) / 64, 256, 0, stream>>>(agg, Wg1, bg1, G1, nullptr, N1);

    // 7. g0 = GraphConv(h0, g0)   (1.6M edges)
    k_gather<1><<<((size_t)N0 * 64 + 255) / 256, 256, 0, stream>>>(h0, rowptr + B_G0, col, od + OB_G0, agg, N0);
    k_mm<128, false, false><<<(N0 + 63) / 64, 256, 0, stream>>>(agg, Wg0, bg0, G0, nullptr, N0);

    // 8. d0 = mean_agg(D1 @ W_dec1 + b, dec1)   (D0 aliases agg — agg consumed above)
    k_mm<128, false, false><<<(N1 + 63) / 64, 256, 0, stream>>>(D1, Wd1, bd1, prj, nullptr, N1);
    k_gather<0><<<((size_t)N0 * 64 + 255) / 256, 256, 0, stream>>>(prj, rowptr + B_D1, col, nullptr, D0, N0);

    // 9. heads (d2 == g2)
    k_head<<<(N0 + 31) / 32, 256, 0, stream>>>(G0, D0, Wh0, bh0, out, N0);
    k_head<<<(N1 + 31) / 32, 256, 0, stream>>>(G1, D1, Wh1, bh1, out + (size_t)N0 * 5, N1);
    k_head<<<(N2 + 31) / 32, 256, 0, stream>>>(G2, G2, Wh2, bh2, out + (size_t)(N0 + N1) * 5, N2);
}